// Round 14
// baseline (1038.757 us; speedup 1.0000x reference)
//
#include <hip/hip_runtime.h>

constexpr int B_  = 8;
constexpr int N_  = 4096;
constexpr int NP1 = 512;
constexpr int NP2 = 256;
constexpr float EPS_ = 1e-5f;

typedef __attribute__((ext_vector_type(8))) short bhalf8;
typedef __attribute__((ext_vector_type(4))) float f32x4;

__device__ inline short f2bf(float f) {
  union { float fv; unsigned u; } v; v.fv = f;
  unsigned r = v.u + 0x7FFFu + ((v.u >> 16) & 1u);
  return (short)(r >> 16);
}
__device__ inline float bf2f(short s) {
  return __uint_as_float(((unsigned)(unsigned short)s) << 16);
}

// packed argmax helpers: key = (khi<<32) | klo, take max
template<int CTRL>
__device__ inline void dpp_amax(unsigned &khi, unsigned &klo) {
  unsigned ohi = (unsigned)__builtin_amdgcn_mov_dpp((int)khi, CTRL, 0xF, 0xF, false);
  unsigned olo = (unsigned)__builtin_amdgcn_mov_dpp((int)klo, CTRL, 0xF, 0xF, false);
  if (ohi > khi || (ohi == khi && olo > klo)) { khi = ohi; klo = olo; }
}
__device__ inline void swz16_amax(unsigned &khi, unsigned &klo) {
  unsigned ohi = (unsigned)__builtin_amdgcn_ds_swizzle((int)khi, 0x401F);
  unsigned olo = (unsigned)__builtin_amdgcn_ds_swizzle((int)klo, 0x401F);
  if (ohi > khi || (ohi == khi && olo > klo)) { khi = ohi; klo = olo; }
}
__device__ inline void x32_amax(unsigned &khi, unsigned &klo) {
  unsigned ohi = (unsigned)__shfl_xor((int)khi, 32);
  unsigned olo = (unsigned)__shfl_xor((int)klo, 32);
  if (ohi > khi || (ohi == khi && olo > klo)) { khi = ohi; klo = olo; }
}
// monotone uint order for arbitrary-sign floats
__device__ inline unsigned ford(float f) {
  unsigned u = __float_as_uint(f);
  return u ^ (((unsigned)((int)u >> 31)) | 0x80000000u);
}

// stats layout (floats): [sum, sumsq] pairs per stage
constexpr int S_BN1 = 0;      // 64+64
constexpr int S_BN2 = 128;    // 64+64
constexpr int S_L0A = 256;    // 128+128
constexpr int S_L0B = 512;    // 128+128
constexpr int S_L1A = 768;    // 256+256
constexpr int S_L1B = 1280;   // 256+256
constexpr int S_TOTAL = 1792;

// ws layout (float offsets)
constexpr size_t OFF_T1   = 0;                          // 2,097,152  (conv1 out; later 'pts'; later mm)
constexpr size_t OFF_YBUF = OFF_T1   + 2097152;         // 16,777,216 (t2 f32 front; ybuf bf16 tail)
constexpr size_t OFF_PTS1 = OFF_YBUF + 16777216;        // 524,288
constexpr size_t OFF_NXYZ = OFF_PTS1 + 524288;          // 12,288
constexpr size_t OFF_WT2C = OFF_NXYZ + 12288;           // 4,096
constexpr size_t OFF_BW0A = OFF_WT2C + 4096;            // 8,192 floats (128*128 bf16)
constexpr size_t OFF_BW0B = OFF_BW0A + 8192;            // 8,192
constexpr size_t OFF_BW1A = OFF_BW0B + 8192;            // 32,768 (256*256 bf16)
constexpr size_t OFF_BW1B = OFF_BW1A + 32768;           // 32,768
constexpr size_t OFF_STAT = OFF_BW1B + 32768;           // 1,792 stats
constexpr size_t OFF_CNT  = OFF_STAT + S_TOTAL;         // 32 ints: [0,1]=conv barriers
constexpr size_t OFF_INT  = OFF_CNT + 32;               // ints from here

__device__ inline void prep_elem(int idx, const float* __restrict__ conv2w,
                                 const float* __restrict__ w0a, const float* __restrict__ w0b,
                                 const float* __restrict__ w1a, const float* __restrict__ w1b,
                                 float* __restrict__ wt2c,
                                 short* __restrict__ b0a, short* __restrict__ b0b,
                                 short* __restrict__ b1a, short* __restrict__ b1b) {
  if (idx < 4096) { int d = idx >> 6, o = idx & 63; wt2c[idx] = conv2w[o*64 + d]; return; }
  idx -= 4096;
  const float* w; short* dst; int D;
  if      (idx <  2048) { w = w0a; dst = b0a; D = 128; }
  else if (idx <  4096) { w = w0b; dst = b0b; D = 128; idx -= 2048; }
  else if (idx < 12288) { w = w1a; dst = b1a; D = 256; idx -= 4096; }
  else                  { w = w1b; dst = b1b; D = 256; idx -= 12288; }
  int kblk = idx / D, o = idx % D;
  const float* src = w + (size_t)o*D + kblk*8;
  bhalf8 pk;
#pragma unroll
  for (int j = 0; j < 8; ++j) pk[j] = f2bf(src[j]);
  *(bhalf8*)&dst[(size_t)idx*8] = pk;
}

struct FpsSmem {
  float lx[4096], ly[4096], lz[4096];
  float sx[512], sy[512], sz[512];
  unsigned long long wk[2][8];
  int seli1[512];
  int seli2[256];
};
struct ConvSmem {
  float xs[3][64];
  float redS[4][64], redQ[4][64];
  float sc[64], sh[64];
  float at[64*68];
};

// ---------------- front: FPS (blocks 0-7) || prep+conv1+conv2+bn2fin (blocks 8-263) ----------------
// Round-8/10/12 proven, byte-identical.
__global__ __launch_bounds__(256) void front_kernel(
    const float* __restrict__ x,
    const float* __restrict__ conv1w, const float* __restrict__ bn1g, const float* __restrict__ bn1b,
    const float* __restrict__ conv2w, const float* __restrict__ bn2g, const float* __restrict__ bn2b,
    const float* __restrict__ w0a, const float* __restrict__ w0b,
    const float* __restrict__ w1a, const float* __restrict__ w1b,
    float* __restrict__ wt2c,
    short* __restrict__ b0a, short* __restrict__ b0b,
    short* __restrict__ b1a, short* __restrict__ b1b,
    float* __restrict__ t1, float* __restrict__ t2,
    float* __restrict__ stats, int* __restrict__ cnt,
    int* __restrict__ sel1, float* __restrict__ nxyz, int* __restrict__ sel2) {
  __shared__ __align__(16) char smem_raw[sizeof(FpsSmem)];
  int t = threadIdx.x;
  if (blockIdx.x < 8) {
    // ================= FPS path =================
    constexpr int NPTS = 4096, NSEL1 = 512, NSEL2 = 256, NT = 256;
    constexpr int K = NPTS / NT, NS = NT / 32;
    FpsSmem& S = *reinterpret_cast<FpsSmem*>(smem_raw);
    int b = blockIdx.x;
    int lane = t & 63, wid = t >> 6;
    const float* cb = x + (size_t)b * 3 * NPTS;
    for (int i = t; i < NPTS; i += NT) {
      S.lx[i] = cb[i]; S.ly[i] = cb[NPTS + i]; S.lz[i] = cb[2*NPTS + i];
    }
    __syncthreads();
    float px[K], py[K], pz[K], dm[K];
#pragma unroll
    for (int k = 0; k < K; ++k) {
      int p = t + k*NT;
      px[k] = S.lx[p]; py[k] = S.ly[p]; pz[k] = S.lz[p];
      dm[k] = 1e10f;
    }
    float cx = S.lx[0], cy = S.ly[0], cz = S.lz[0];
    if (t == 0) { S.seli1[0] = 0; S.sx[0] = cx; S.sy[0] = cy; S.sz[0] = cz; }
    for (int it = 1; it < NSEL1; ++it) {
      float bv = -1.f; int bi = 0;
#pragma unroll
      for (int k = 0; k < K; ++k) {
        float dx = px[k]-cx, dy = py[k]-cy, dz = pz[k]-cz;
        float d = dx*dx + dy*dy + dz*dz;
        float nd = fminf(dm[k], d);
        dm[k] = nd;
        if (nd > bv) { bv = nd; bi = t + k*NT; }
      }
      unsigned khi = __float_as_uint(bv), klo = ~(unsigned)bi;
      dpp_amax<0xB1>(khi, klo);
      dpp_amax<0x4E>(khi, klo);
      dpp_amax<0x141>(khi, klo);
      dpp_amax<0x140>(khi, klo);
      swz16_amax(khi, klo);
      int p = it & 1;
      if ((lane & 31) == 0)
        S.wk[p][wid*2 + (lane >> 5)] = ((unsigned long long)khi << 32) | klo;
      __syncthreads();
      unsigned long long best = S.wk[p][0];
#pragma unroll
      for (int i2 = 1; i2 < NS; ++i2) { unsigned long long v2 = S.wk[p][i2]; if (v2 > best) best = v2; }
      int Bi = (int)(~(unsigned)best);
      cx = S.lx[Bi]; cy = S.ly[Bi]; cz = S.lz[Bi];
      if (t == 0) { S.seli1[it] = Bi; S.sx[it] = cx; S.sy[it] = cy; S.sz[it] = cz; }
    }
    __syncthreads();
    if (t < 64) {
      // ---- level 2, single wave (wave 0), zero barriers ----
      constexpr int K2 = NSEL1 / 64;
      float qx[K2], qy[K2], qz[K2], dm2[K2];
#pragma unroll
      for (int k = 0; k < K2; ++k) {
        int p = t + k*64;
        qx[k] = S.sx[p]; qy[k] = S.sy[p]; qz[k] = S.sz[p];
        dm2[k] = 1e10f;
      }
      cx = S.sx[0]; cy = S.sy[0]; cz = S.sz[0];
      if (t == 0) S.seli2[0] = 0;
      for (int it = 1; it < NSEL2; ++it) {
        float bv = -1.f; int bi = 0;
#pragma unroll
        for (int k = 0; k < K2; ++k) {
          float dx = qx[k]-cx, dy = qy[k]-cy, dz = qz[k]-cz;
          float d = dx*dx + dy*dy + dz*dz;
          float nd = fminf(dm2[k], d);
          dm2[k] = nd;
          if (nd > bv) { bv = nd; bi = t + k*64; }
        }
        unsigned khi = __float_as_uint(bv), klo = ~(unsigned)bi;
        dpp_amax<0xB1>(khi, klo);
        dpp_amax<0x4E>(khi, klo);
        dpp_amax<0x141>(khi, klo);
        dpp_amax<0x140>(khi, klo);
        swz16_amax(khi, klo);
        x32_amax(khi, klo);
        int Bi = (int)~klo;
        cx = S.sx[Bi]; cy = S.sy[Bi]; cz = S.sz[Bi];
        if (t == 0) S.seli2[it] = Bi;
      }
    } else {
      for (int i = t - 64; i < NSEL1; i += NT - 64) {
        sel1[(size_t)b*NSEL1 + i] = S.seli1[i];
        float* q = nxyz + ((size_t)b*NSEL1 + i)*3;
        q[0] = S.sx[i]; q[1] = S.sy[i]; q[2] = S.sz[i];
      }
    }
    __syncthreads();
    for (int i = t; i < NSEL2; i += NT) sel2[(size_t)b*NSEL2 + i] = S.seli2[i];
    return;
  }
  // ================= conv path =================
  ConvSmem& C = *reinterpret_cast<ConvSmem*>(smem_raw);
  int cb = blockIdx.x - 8;   // 0..255
  { int idx = cb*256 + t;
    if (idx < 24576) prep_elem(idx, conv2w, w0a, w0b, w1a, w1b, wt2c, b0a, b0b, b1a, b1b); }
  for (int tile = cb; tile < 512; tile += 256) {
    int b = tile >> 6, n0 = (tile & 63) << 6;
    if (t < 192) { int c = t >> 6, nl = t & 63; C.xs[c][nl] = x[((size_t)b*3 + c)*N_ + n0 + nl]; }
    __syncthreads();
    int o = t & 63, ng = t >> 6;
    float w0 = conv1w[o*3+0], w1 = conv1w[o*3+1], w2 = conv1w[o*3+2];
    float ls = 0.f, lq = 0.f;
#pragma unroll
    for (int k = 0; k < 16; ++k) {
      int nl = ng*16 + k;
      float y = C.xs[0][nl]*w0 + C.xs[1][nl]*w1 + C.xs[2][nl]*w2;
      t1[((size_t)b*N_ + n0 + nl)*64 + o] = y;
      ls += y; lq += y*y;
    }
    C.redS[ng][o] = ls; C.redQ[ng][o] = lq;
    __syncthreads();
    if (t < 64) {
      float s = C.redS[0][t]+C.redS[1][t]+C.redS[2][t]+C.redS[3][t];
      float q = C.redQ[0][t]+C.redQ[1][t]+C.redQ[2][t]+C.redQ[3][t];
      atomicAdd(&stats[S_BN1 + t], s);
      atomicAdd(&stats[S_BN1 + 64 + t], q);
    }
    __syncthreads();
  }
  if (t == 0) {
    __threadfence();
    __hip_atomic_fetch_add(&cnt[0], 1, __ATOMIC_ACQ_REL, __HIP_MEMORY_SCOPE_AGENT);
    while (__hip_atomic_load(&cnt[0], __ATOMIC_ACQUIRE, __HIP_MEMORY_SCOPE_AGENT) < 256)
      __builtin_amdgcn_s_sleep(8);
    __threadfence();
  }
  __syncthreads();
  if (t < 64) {
    float m = stats[S_BN1 + t] * (1.f/32768.f);
    float v = stats[S_BN1 + 64 + t] * (1.f/32768.f) - m*m;
    float s = bn1g[t] * rsqrtf(v + EPS_);
    C.sc[t] = s; C.sh[t] = bn1b[t] - m*s;
  }
  __syncthreads();
  for (int tile = cb; tile < 512; tile += 256) {
    int b = tile >> 6, n0 = (tile & 63) << 6;
    constexpr int P = 68;
    for (int e = t; e < 4096; e += 256) {
      int nl = e >> 6, c = e & 63;
      float v = t1[((size_t)b*N_ + n0 + nl)*64 + c];
      C.at[c*P + nl] = fmaxf(v*C.sc[c] + C.sh[c], 0.f);
    }
    __syncthreads();
    int o = t & 63, ng = t >> 6;
    float acc[16];
#pragma unroll
    for (int k = 0; k < 16; ++k) acc[k] = 0.f;
    for (int i = 0; i < 64; ++i) {
      float wv = wt2c[i*64 + o];
      const float* ar = &C.at[i*P + ng*16];
#pragma unroll
      for (int k = 0; k < 16; k += 4) {
        float4 a4 = *(const float4*)(ar + k);
        acc[k+0] += a4.x*wv; acc[k+1] += a4.y*wv;
        acc[k+2] += a4.z*wv; acc[k+3] += a4.w*wv;
      }
    }
    float ls = 0.f, lq = 0.f;
#pragma unroll
    for (int k = 0; k < 16; ++k) {
      float y = acc[k];
      t2[((size_t)b*N_ + n0 + ng*16 + k)*64 + o] = y;
      ls += y; lq += y*y;
    }
    C.redS[ng][o] = ls; C.redQ[ng][o] = lq;
    __syncthreads();
    if (t < 64) {
      float s = C.redS[0][t]+C.redS[1][t]+C.redS[2][t]+C.redS[3][t];
      float q = C.redQ[0][t]+C.redQ[1][t]+C.redQ[2][t]+C.redQ[3][t];
      atomicAdd(&stats[S_BN2 + t], s);
      atomicAdd(&stats[S_BN2 + 64 + t], q);
    }
    __syncthreads();
  }
  if (t == 0) {
    __threadfence();
    __hip_atomic_fetch_add(&cnt[1], 1, __ATOMIC_ACQ_REL, __HIP_MEMORY_SCOPE_AGENT);
    while (__hip_atomic_load(&cnt[1], __ATOMIC_ACQUIRE, __HIP_MEMORY_SCOPE_AGENT) < 256)
      __builtin_amdgcn_s_sleep(8);
    __threadfence();
  }
  __syncthreads();
  {
    int o = t & 63;
    float m = stats[S_BN2 + o] * (1.f/32768.f);
    float v = stats[S_BN2 + 64 + o] * (1.f/32768.f) - m*m;
    float s = bn2g[o] * rsqrtf(v + EPS_);
    float sh = bn2b[o] - m*s;
    for (int tile = cb; tile < 512; tile += 256)
#pragma unroll
      for (int j = 0; j < 16; ++j) {
        size_t idx = (size_t)tile*4096 + j*256 + t;
        t1[idx] = fmaxf(t2[idx]*s + sh, 0.f);
      }
  }
}

// ---------------- kNN: wave-per-query, fully in-register, zero barriers (round-10/12 proven) ----------------
template<int NDST, bool XLAY>
__device__ inline void wave_knn(const float* __restrict__ db,
                                float qx, float qy, float qz,
                                int* __restrict__ out32) {
  constexpr int K = NDST / 64;
  int lane = threadIdx.x & 63;
  float q2 = (qx*qx + qy*qy) + qz*qz;
  float d2r[K];
#pragma unroll
  for (int k = 0; k < K; ++k) {
    int j = lane + k*64;
    float xx, yy, zz;
    if (XLAY) { xx = db[j]; yy = db[NDST + j]; zz = db[2*NDST + j]; }
    else      { xx = db[j*3]; yy = db[j*3+1]; zz = db[j*3+2]; }
    float dot = (qx*xx + qy*yy) + qz*zz;
    float p2  = (xx*xx + yy*yy) + zz*zz;
    d2r[k] = (q2 - 2.f*dot) + p2;     // same expansion as reference
  }
  int myout = 0;
  for (int r = 0; r < 32; ++r) {
    float bv = 3e38f; int bi = lane;
#pragma unroll
    for (int k = 0; k < K; ++k) {
      float v = d2r[k];
      if (v < bv) { bv = v; bi = lane + k*64; }   // k ascending => lowest index on tie
    }
    unsigned khi = ~ford(bv), klo = ~(unsigned)bi;
    dpp_amax<0xB1>(khi, klo);
    dpp_amax<0x4E>(khi, klo);
    dpp_amax<0x141>(khi, klo);
    dpp_amax<0x140>(khi, klo);
    swz16_amax(khi, klo);
    x32_amax(khi, klo);                 // wave-uniform winner
    int Bi = (int)~klo;
    if (lane == r) myout = Bi;
#pragma unroll
    for (int k = 0; k < K; ++k)         // compile-time index; no scratch (rule #20)
      if (lane + k*64 == Bi) d2r[k] = 3e38f;
  }
  if (lane < 32) out32[lane] = myout;
}

// ---------------- GEMM1 (+fused per-block kNN): gather -> bf16 MFMA -> ybuf(bf16) + stats ----------------
// Each block owns 2 (b,n) groups; their 32-NN lists are consumed ONLY here, so waves 0-1
// compute them in-register (round-10 wave_knn, identical selection semantics) straight into
// LDS kid_s — no global knn buffers, no extra kernel, no cross-block sync.
template<int D, int PW, int NP, int SRCN, int SOFF, int NDST, bool XLAY>
__global__ __launch_bounds__(256) void gemm1_kernel(
    const float* __restrict__ qdb,   // kNN search db: x (XLAY) or nxyz slab base (!XLAY)
    const float* __restrict__ pts,   // gather source
    const int* __restrict__ cent, const int* __restrict__ qmap,
    const float* __restrict__ nxyz, const short* __restrict__ bw,
    short* __restrict__ ybuf, float* __restrict__ stats) {
  constexpr int KB = D/8;
  __shared__ __align__(16) short As[64*D];
  __shared__ float cen_s[2*PW];
  __shared__ int kid_s[64];
  __shared__ float sstat[2*D];
  int t = threadIdx.x, blk = blockIdx.x;
  int g0 = blk*2;
  {
    int wid = t >> 6;
    if (wid < 2) {
      int g = g0 + wid;
      int b = g / NP, qi = g - b*NP;
      int qrow = b*NP1 + (qmap ? qmap[g] : qi);
      const float* qp = nxyz + (size_t)qrow*3;
      const float* db = XLAY ? (qdb + (size_t)b*3*SRCN) : (nxyz + (size_t)b*NP1*3);
      wave_knn<NDST, XLAY>(db, qp[0], qp[1], qp[2], &kid_s[wid*32]);
    }
  }
  for (int i = t; i < 2*PW; i += 256) {
    int grp = i / PW, d = i % PW;
    int g = g0 + grp; int b = g / NP; int ci = cent[g];
    cen_s[i] = pts[((size_t)b*SRCN + ci)*PW + d];
  }
  for (int i = t; i < 2*D; i += 256) sstat[i] = 0.f;
  __syncthreads();
  for (int task = t; task < 64*KB; task += 256) {
    int row = task / KB, c = task % KB;
    int grp = row >> 5;
    int g = g0 + grp; int b = g / NP;
    int d = c*8;
    float v0,v1,v2,v3,v4,v5,v6,v7;
    if (d < PW) {
      const float* src = pts + ((size_t)b*SRCN + kid_s[row])*PW + d;
      float4 x0 = *(const float4*)src, x1 = *(const float4*)(src+4);
      const float* cc = &cen_s[grp*PW + d];
      v0=x0.x-cc[0]; v1=x0.y-cc[1]; v2=x0.z-cc[2]; v3=x0.w-cc[3];
      v4=x1.x-cc[4]; v5=x1.y-cc[5]; v6=x1.z-cc[6]; v7=x1.w-cc[7];
    } else {
      const float* cc = &cen_s[grp*PW + d - PW];
      v0=cc[0]; v1=cc[1]; v2=cc[2]; v3=cc[3]; v4=cc[4]; v5=cc[5]; v6=cc[6]; v7=cc[7];
    }
    bhalf8 pk;
    pk[0]=f2bf(v0); pk[1]=f2bf(v1); pk[2]=f2bf(v2); pk[3]=f2bf(v3);
    pk[4]=f2bf(v4); pk[5]=f2bf(v5); pk[6]=f2bf(v6); pk[7]=f2bf(v7);
    int a16 = row*KB + (c ^ (row & 7));
    *(bhalf8*)&As[a16*8] = pk;
  }
  __syncthreads();
  int w = t >> 6, l = t & 63, lr = l & 15, lg = l >> 4;
  f32x4 acc[D/16];
#pragma unroll
  for (int ct = 0; ct < D/16; ++ct) acc[ct] = (f32x4){0.f,0.f,0.f,0.f};
  int r = w*16 + lr;
#pragma unroll
  for (int kg = 0; kg < D/32; ++kg) {
    int c = (kg*4 + lg) ^ (r & 7);
    bhalf8 af = *(const bhalf8*)&As[(r*KB + c)*8];
#pragma unroll
    for (int ct = 0; ct < D/16; ++ct) {
      bhalf8 bf = *(const bhalf8*)&bw[((size_t)(kg*4 + lg)*D + ct*16 + lr)*8];
      acc[ct] = __builtin_amdgcn_mfma_f32_16x16x32_bf16(af, bf, acc[ct], 0, 0, 0);
    }
  }
  __syncthreads();   // all As reads complete; reuse As as bf16 C tile
  int lrow = w*16 + lg*4;
#pragma unroll
  for (int ct = 0; ct < D/16; ++ct) {
    int col = ct*16 + lr;
    f32x4 a = acc[ct];
    As[(lrow+0)*D + col] = f2bf(a[0]);
    As[(lrow+1)*D + col] = f2bf(a[1]);
    As[(lrow+2)*D + col] = f2bf(a[2]);
    As[(lrow+3)*D + col] = f2bf(a[3]);
    float s = a[0]+a[1]+a[2]+a[3];
    float q = a[0]*a[0]+a[1]*a[1]+a[2]*a[2]+a[3]*a[3];
    s += __shfl_xor(s, 16); q += __shfl_xor(q, 16);
    s += __shfl_xor(s, 32); q += __shfl_xor(q, 32);
    if (lg == 0) { atomicAdd(&sstat[col], s); atomicAdd(&sstat[D+col], q); }
  }
  __syncthreads();
  {
    short* yp = ybuf + (size_t)blk*64*D;
    for (int i = t; i < 64*D/8; i += 256)
      *(bhalf8*)&yp[i*8] = *(const bhalf8*)&As[i*8];
  }
  for (int i = t; i < 2*D; i += 256) atomicAdd(&stats[SOFF+i], sstat[i]);
}

// ---------------- GEMM2: bf16 y-in, bn+relu -> bf16 MFMA -> per-group max/min + stats ----------------
template<int D, int SIN, int SOUT, int CNT>
__global__ __launch_bounds__(256) void gemm2_kernel(
    const float* __restrict__ g1, const float* __restrict__ b1,
    const short* __restrict__ bw, const short* __restrict__ ybuf,
    float* __restrict__ mm, float* __restrict__ stats) {
  __shared__ __align__(16) float scsh[2*D];
  __shared__ float sstat[2*D];
  __shared__ float wmax[4][D], wmin[4][D];
  int t = threadIdx.x, blk = blockIdx.x;
  for (int i = t; i < D; i += 256) {
    float m = stats[SIN + i] * (1.f/(float)CNT);
    float v = stats[SIN + D + i] * (1.f/(float)CNT) - m*m;
    float s = g1[i] * rsqrtf(v + EPS_);
    scsh[i] = s; scsh[D+i] = b1[i] - m*s;
  }
  for (int i = t; i < 2*D; i += 256) sstat[i] = 0.f;
  __syncthreads();
  int w = t >> 6, l = t & 63, lr = l & 15, lg = l >> 4;
  size_t row = (size_t)blk*64 + w*16 + lr;
  const short* yrow = ybuf + row*D;
  f32x4 acc[D/16];
#pragma unroll
  for (int ct = 0; ct < D/16; ++ct) acc[ct] = (f32x4){0.f,0.f,0.f,0.f};
#pragma unroll
  for (int kg = 0; kg < D/32; ++kg) {
    int k = kg*32 + lg*8;
    bhalf8 yv = *(const bhalf8*)(yrow + k);
    bhalf8 af;
#pragma unroll
    for (int j = 0; j < 8; ++j)
      af[j] = f2bf(fmaxf(bf2f(yv[j])*scsh[k+j] + scsh[D+k+j], 0.f));
#pragma unroll
    for (int ct = 0; ct < D/16; ++ct) {
      bhalf8 bf = *(const bhalf8*)&bw[((size_t)(kg*4 + lg)*D + ct*16 + lr)*8];
      acc[ct] = __builtin_amdgcn_mfma_f32_16x16x32_bf16(af, bf, acc[ct], 0, 0, 0);
    }
  }
#pragma unroll
  for (int ct = 0; ct < D/16; ++ct) {
    int col = ct*16 + lr;
    f32x4 a = acc[ct];
    float mx = fmaxf(fmaxf(a[0], a[1]), fmaxf(a[2], a[3]));
    float mn = fminf(fminf(a[0], a[1]), fminf(a[2], a[3]));
    mx = fmaxf(mx, __shfl_xor(mx, 16)); mn = fminf(mn, __shfl_xor(mn, 16));
    mx = fmaxf(mx, __shfl_xor(mx, 32)); mn = fminf(mn, __shfl_xor(mn, 32));
    if (lg == 0) { wmax[w][col] = mx; wmin[w][col] = mn; }
    float s = a[0]+a[1]+a[2]+a[3];
    float q = a[0]*a[0]+a[1]*a[1]+a[2]*a[2]+a[3]*a[3];
    s += __shfl_xor(s, 16); q += __shfl_xor(q, 16);
    s += __shfl_xor(s, 32); q += __shfl_xor(q, 32);
    if (lg == 0) { atomicAdd(&sstat[col], s); atomicAdd(&sstat[D+col], q); }
  }
  __syncthreads();
  for (int i = t; i < 2*D; i += 256) {
    int g = i / D, col = i - g*D;
    float mx = fmaxf(wmax[2*g][col], wmax[2*g+1][col]);
    float mn = fminf(wmin[2*g][col], wmin[2*g+1][col]);
    float* mp = mm + ((size_t)blk*2 + g)*2*D;
    mp[col] = mx; mp[D + col] = mn;
    atomicAdd(&stats[SOUT+i], sstat[i]);
  }
}

// ---------------- finish: bn2 + relu applied to per-group max/min (exact, elementwise) ----------------
template<int D, int NP, int SOFF, int CNT, bool TR>
__global__ __launch_bounds__(256) void le3_kernel(
    const float* __restrict__ g2, const float* __restrict__ b2,
    const float* __restrict__ mm, const float* __restrict__ stats,
    float* __restrict__ out) {
  int idx = blockIdx.x*256 + threadIdx.x;
  int g = idx / D, o = idx - g*D;
  float m = stats[SOFF + o] * (1.f/(float)CNT);
  float v = stats[SOFF + D + o] * (1.f/(float)CNT) - m*m;
  float s = g2[o] * rsqrtf(v + EPS_);
  float sh = b2[o] - m*s;
  const float* mp = mm + (size_t)g*2*D;
  float pick = (s >= 0.f) ? mp[o] : mp[D + o];
  float r = fmaxf(pick*s + sh, 0.f);
  if (TR) { int b = g / NP, n = g - b*NP; out[((size_t)b*D + o)*NP + n] = r; }
  else    out[(size_t)g*D + o] = r;
}

// ---------------- host ----------------
extern "C" void kernel_launch(void* const* d_in, const int* in_sizes, int n_in,
                              void* d_out, int out_size, void* d_ws, size_t ws_size,
                              hipStream_t stream) {
  (void)in_sizes; (void)n_in; (void)out_size; (void)ws_size;
  const float* x       = (const float*)d_in[0];
  const float* conv1_w = (const float*)d_in[1];
  const float* bn1_g   = (const float*)d_in[2];
  const float* bn1_b   = (const float*)d_in[3];
  const float* conv2_w = (const float*)d_in[4];
  const float* bn2_g   = (const float*)d_in[5];
  const float* bn2_b   = (const float*)d_in[6];
  const float* le0_w1  = (const float*)d_in[7];
  const float* le0_g1  = (const float*)d_in[8];
  const float* le0_b1  = (const float*)d_in[9];
  const float* le0_w2  = (const float*)d_in[10];
  const float* le0_g2  = (const float*)d_in[11];
  const float* le0_b2  = (const float*)d_in[12];
  const float* le1_w1  = (const float*)d_in[13];
  const float* le1_g1  = (const float*)d_in[14];
  const float* le1_b1  = (const float*)d_in[15];
  const float* le1_w2  = (const float*)d_in[16];
  const float* le1_g2  = (const float*)d_in[17];
  const float* le1_b2  = (const float*)d_in[18];

  float* ws   = (float*)d_ws;
  float* t1   = ws + OFF_T1;      // conv1 out; then 'pts'; later mm buffer
  float* t2   = ws + OFF_YBUF;    // conv2 f32 buffer (front phase)
  short* ybuf = (short*)(ws + OFF_YBUF);  // LE y1 buffer, bf16 (tail phase)
  float* mm   = t1;
  float* pts1 = ws + OFF_PTS1;
  float* nxyz = ws + OFF_NXYZ;
  float* wt2c = ws + OFF_WT2C;
  short* bw0a = (short*)(ws + OFF_BW0A);
  short* bw0b = (short*)(ws + OFF_BW0B);
  short* bw1a = (short*)(ws + OFF_BW1A);
  short* bw1b = (short*)(ws + OFF_BW1B);
  float* stats = ws + OFF_STAT;
  int*   cnt   = (int*)(ws + OFF_CNT);
  int* fps1 = (int*)(ws + OFF_INT);
  int* fps2 = fps1 + 4096;

  // zero stats + barrier counters (captured; re-zeroed on every replay)
  hipMemsetAsync(stats, 0, (S_TOTAL + 32)*sizeof(float), stream);
  front_kernel<<<264, 256, 0, stream>>>(x,
      conv1_w, bn1_g, bn1_b, conv2_w, bn2_g, bn2_b,
      le0_w1, le0_w2, le1_w1, le1_w2,
      wt2c, bw0a, bw0b, bw1a, bw1b,
      t1, t2, stats, cnt, fps1, nxyz, fps2);

  gemm1_kernel<128,  64, 512, 4096, S_L0A, 4096, true ><<<2048, 256, 0, stream>>>(
      x, t1, fps1, nullptr, nxyz, bw0a, ybuf, stats);
  gemm2_kernel<128, S_L0A, S_L0B, 131072><<<2048, 256, 0, stream>>>(le0_g1, le0_b1, bw0b, ybuf, mm, stats);
  le3_kernel<128, 512, S_L0B, 131072, false><<<2048, 256, 0, stream>>>(le0_g2, le0_b2, mm, stats, pts1);

  gemm1_kernel<256, 128, 256,  512, S_L1A,  512, false><<<1024, 256, 0, stream>>>(
      nxyz, pts1, fps2, fps2, nxyz, bw1a, ybuf, stats);
  gemm2_kernel<256, S_L1A, S_L1B, 65536><<<1024, 256, 0, stream>>>(le1_g1, le1_b1, bw1b, ybuf, mm, stats);
  le3_kernel<256, 256, S_L1B, 65536, true><<<2048, 256, 0, stream>>>(le1_g2, le1_b2, mm, stats, (float*)d_out);
}

// Round 15
// 924.223 us; speedup vs baseline: 1.1239x; 1.1239x over previous
//
#include <hip/hip_runtime.h>

constexpr int B_  = 8;
constexpr int N_  = 4096;
constexpr int NP1 = 512;
constexpr int NP2 = 256;
constexpr float EPS_ = 1e-5f;

typedef __attribute__((ext_vector_type(8))) short bhalf8;
typedef __attribute__((ext_vector_type(4))) float f32x4;

__device__ inline short f2bf(float f) {
  union { float fv; unsigned u; } v; v.fv = f;
  unsigned r = v.u + 0x7FFFu + ((v.u >> 16) & 1u);
  return (short)(r >> 16);
}
__device__ inline float bf2f(short s) {
  return __uint_as_float(((unsigned)(unsigned short)s) << 16);
}

// packed argmax helpers: key = (khi<<32) | klo, take max
template<int CTRL>
__device__ inline void dpp_amax(unsigned &khi, unsigned &klo) {
  unsigned ohi = (unsigned)__builtin_amdgcn_mov_dpp((int)khi, CTRL, 0xF, 0xF, false);
  unsigned olo = (unsigned)__builtin_amdgcn_mov_dpp((int)klo, CTRL, 0xF, 0xF, false);
  if (ohi > khi || (ohi == khi && olo > klo)) { khi = ohi; klo = olo; }
}
__device__ inline void swz16_amax(unsigned &khi, unsigned &klo) {
  unsigned ohi = (unsigned)__builtin_amdgcn_ds_swizzle((int)khi, 0x401F);
  unsigned olo = (unsigned)__builtin_amdgcn_ds_swizzle((int)klo, 0x401F);
  if (ohi > khi || (ohi == khi && olo > klo)) { khi = ohi; klo = olo; }
}
__device__ inline void x32_amax(unsigned &khi, unsigned &klo) {
  unsigned ohi = (unsigned)__shfl_xor((int)khi, 32);
  unsigned olo = (unsigned)__shfl_xor((int)klo, 32);
  if (ohi > khi || (ohi == khi && olo > klo)) { khi = ohi; klo = olo; }
}
// monotone uint order for arbitrary-sign floats
__device__ inline unsigned ford(float f) {
  unsigned u = __float_as_uint(f);
  return u ^ (((unsigned)((int)u >> 31)) | 0x80000000u);
}

// stats layout (floats): [sum, sumsq] pairs per stage
constexpr int S_BN1 = 0;      // 64+64
constexpr int S_BN2 = 128;    // 64+64
constexpr int S_L0A = 256;    // 128+128
constexpr int S_L0B = 512;    // 128+128
constexpr int S_L1A = 768;    // 256+256
constexpr int S_L1B = 1280;   // 256+256
constexpr int S_TOTAL = 1792;

// ws layout (float offsets)
constexpr size_t OFF_T1   = 0;                          // 2,097,152  (conv1 out; later 'pts'; later mm)
constexpr size_t OFF_YBUF = OFF_T1   + 2097152;         // 16,777,216 (t2 f32 front; ybuf bf16 tail)
constexpr size_t OFF_PTS1 = OFF_YBUF + 16777216;        // 524,288
constexpr size_t OFF_NXYZ = OFF_PTS1 + 524288;          // 12,288
constexpr size_t OFF_WT2C = OFF_NXYZ + 12288;           // 4,096
constexpr size_t OFF_BW0A = OFF_WT2C + 4096;            // 8,192 floats (128*128 bf16)
constexpr size_t OFF_BW0B = OFF_BW0A + 8192;            // 8,192
constexpr size_t OFF_BW1A = OFF_BW0B + 8192;            // 32,768 (256*256 bf16)
constexpr size_t OFF_BW1B = OFF_BW1A + 32768;           // 32,768
constexpr size_t OFF_STAT = OFF_BW1B + 32768;           // 1,792 stats
constexpr size_t OFF_CNT  = OFF_STAT + S_TOTAL;         // 32 ints: [0,1]=conv barriers
constexpr size_t OFF_INT  = OFF_CNT + 32;               // ints from here

__device__ inline void prep_elem(int idx, const float* __restrict__ conv2w,
                                 const float* __restrict__ w0a, const float* __restrict__ w0b,
                                 const float* __restrict__ w1a, const float* __restrict__ w1b,
                                 float* __restrict__ wt2c,
                                 short* __restrict__ b0a, short* __restrict__ b0b,
                                 short* __restrict__ b1a, short* __restrict__ b1b) {
  if (idx < 4096) { int d = idx >> 6, o = idx & 63; wt2c[idx] = conv2w[o*64 + d]; return; }
  idx -= 4096;
  const float* w; short* dst; int D;
  if      (idx <  2048) { w = w0a; dst = b0a; D = 128; }
  else if (idx <  4096) { w = w0b; dst = b0b; D = 128; idx -= 2048; }
  else if (idx < 12288) { w = w1a; dst = b1a; D = 256; idx -= 4096; }
  else                  { w = w1b; dst = b1b; D = 256; idx -= 12288; }
  int kblk = idx / D, o = idx % D;
  const float* src = w + (size_t)o*D + kblk*8;
  bhalf8 pk;
#pragma unroll
  for (int j = 0; j < 8; ++j) pk[j] = f2bf(src[j]);
  *(bhalf8*)&dst[(size_t)idx*8] = pk;
}

struct FpsSmem {
  float lx[4096], ly[4096], lz[4096];
  float sx[512], sy[512], sz[512];
  unsigned long long wk[2][8];
  int seli1[512];
  int seli2[256];
};
struct ConvSmem {
  float xs[3][64];
  float redS[4][64], redQ[4][64];
  float sc[64], sh[64];
  float at[64*68];
};

// ---------------- front: FPS (blocks 0-7) || prep+conv1+conv2+bn2fin (blocks 8-263) ----------------
// Round-8/10/12 proven. FPS blocks fully independent; conv blocks sync among themselves via
// device-scope counter barriers. 264 blocks x 58.5KB LDS => 2 blocks/CU => co-resident, 2x margin.
__global__ __launch_bounds__(256) void front_kernel(
    const float* __restrict__ x,
    const float* __restrict__ conv1w, const float* __restrict__ bn1g, const float* __restrict__ bn1b,
    const float* __restrict__ conv2w, const float* __restrict__ bn2g, const float* __restrict__ bn2b,
    const float* __restrict__ w0a, const float* __restrict__ w0b,
    const float* __restrict__ w1a, const float* __restrict__ w1b,
    float* __restrict__ wt2c,
    short* __restrict__ b0a, short* __restrict__ b0b,
    short* __restrict__ b1a, short* __restrict__ b1b,
    float* __restrict__ t1, float* __restrict__ t2,
    float* __restrict__ stats, int* __restrict__ cnt,
    int* __restrict__ sel1, float* __restrict__ nxyz, int* __restrict__ sel2) {
  __shared__ __align__(16) char smem_raw[sizeof(FpsSmem)];
  int t = threadIdx.x;
  if (blockIdx.x < 8) {
    // ================= FPS path =================
    constexpr int NPTS = 4096, NSEL1 = 512, NSEL2 = 256, NT = 256;
    constexpr int K = NPTS / NT, NS = NT / 32;
    FpsSmem& S = *reinterpret_cast<FpsSmem*>(smem_raw);
    int b = blockIdx.x;
    int lane = t & 63, wid = t >> 6;
    const float* cb = x + (size_t)b * 3 * NPTS;
    for (int i = t; i < NPTS; i += NT) {
      S.lx[i] = cb[i]; S.ly[i] = cb[NPTS + i]; S.lz[i] = cb[2*NPTS + i];
    }
    __syncthreads();
    float px[K], py[K], pz[K], dm[K];
#pragma unroll
    for (int k = 0; k < K; ++k) {
      int p = t + k*NT;
      px[k] = S.lx[p]; py[k] = S.ly[p]; pz[k] = S.lz[p];
      dm[k] = 1e10f;
    }
    float cx = S.lx[0], cy = S.ly[0], cz = S.lz[0];
    if (t == 0) { S.seli1[0] = 0; S.sx[0] = cx; S.sy[0] = cy; S.sz[0] = cz; }
    for (int it = 1; it < NSEL1; ++it) {
      float bv = -1.f; int bi = 0;
#pragma unroll
      for (int k = 0; k < K; ++k) {
        float dx = px[k]-cx, dy = py[k]-cy, dz = pz[k]-cz;
        float d = dx*dx + dy*dy + dz*dz;
        float nd = fminf(dm[k], d);
        dm[k] = nd;
        if (nd > bv) { bv = nd; bi = t + k*NT; }
      }
      unsigned khi = __float_as_uint(bv), klo = ~(unsigned)bi;
      dpp_amax<0xB1>(khi, klo);
      dpp_amax<0x4E>(khi, klo);
      dpp_amax<0x141>(khi, klo);
      dpp_amax<0x140>(khi, klo);
      swz16_amax(khi, klo);
      int p = it & 1;
      if ((lane & 31) == 0)
        S.wk[p][wid*2 + (lane >> 5)] = ((unsigned long long)khi << 32) | klo;
      __syncthreads();
      unsigned long long best = S.wk[p][0];
#pragma unroll
      for (int i2 = 1; i2 < NS; ++i2) { unsigned long long v2 = S.wk[p][i2]; if (v2 > best) best = v2; }
      int Bi = (int)(~(unsigned)best);
      cx = S.lx[Bi]; cy = S.ly[Bi]; cz = S.lz[Bi];
      if (t == 0) { S.seli1[it] = Bi; S.sx[it] = cx; S.sy[it] = cy; S.sz[it] = cz; }
    }
    __syncthreads();
    if (t < 64) {
      // ---- level 2, single wave (wave 0), zero barriers ----
      constexpr int K2 = NSEL1 / 64;
      float qx[K2], qy[K2], qz[K2], dm2[K2];
#pragma unroll
      for (int k = 0; k < K2; ++k) {
        int p = t + k*64;
        qx[k] = S.sx[p]; qy[k] = S.sy[p]; qz[k] = S.sz[p];
        dm2[k] = 1e10f;
      }
      cx = S.sx[0]; cy = S.sy[0]; cz = S.sz[0];
      if (t == 0) S.seli2[0] = 0;
      for (int it = 1; it < NSEL2; ++it) {
        float bv = -1.f; int bi = 0;
#pragma unroll
        for (int k = 0; k < K2; ++k) {
          float dx = qx[k]-cx, dy = qy[k]-cy, dz = qz[k]-cz;
          float d = dx*dx + dy*dy + dz*dz;
          float nd = fminf(dm2[k], d);
          dm2[k] = nd;
          if (nd > bv) { bv = nd; bi = t + k*64; }
        }
        unsigned khi = __float_as_uint(bv), klo = ~(unsigned)bi;
        dpp_amax<0xB1>(khi, klo);
        dpp_amax<0x4E>(khi, klo);
        dpp_amax<0x141>(khi, klo);
        dpp_amax<0x140>(khi, klo);
        swz16_amax(khi, klo);
        x32_amax(khi, klo);
        int Bi = (int)~klo;
        cx = S.sx[Bi]; cy = S.sy[Bi]; cz = S.sz[Bi];
        if (t == 0) S.seli2[it] = Bi;
      }
    } else {
      for (int i = t - 64; i < NSEL1; i += NT - 64) {
        sel1[(size_t)b*NSEL1 + i] = S.seli1[i];
        float* q = nxyz + ((size_t)b*NSEL1 + i)*3;
        q[0] = S.sx[i]; q[1] = S.sy[i]; q[2] = S.sz[i];
      }
    }
    __syncthreads();
    for (int i = t; i < NSEL2; i += NT) sel2[(size_t)b*NSEL2 + i] = S.seli2[i];
    return;
  }
  // ================= conv path =================
  ConvSmem& C = *reinterpret_cast<ConvSmem*>(smem_raw);
  int cb = blockIdx.x - 8;   // 0..255
  { int idx = cb*256 + t;
    if (idx < 24576) prep_elem(idx, conv2w, w0a, w0b, w1a, w1b, wt2c, b0a, b0b, b1a, b1b); }
  for (int tile = cb; tile < 512; tile += 256) {
    int b = tile >> 6, n0 = (tile & 63) << 6;
    if (t < 192) { int c = t >> 6, nl = t & 63; C.xs[c][nl] = x[((size_t)b*3 + c)*N_ + n0 + nl]; }
    __syncthreads();
    int o = t & 63, ng = t >> 6;
    float w0 = conv1w[o*3+0], w1 = conv1w[o*3+1], w2 = conv1w[o*3+2];
    float ls = 0.f, lq = 0.f;
#pragma unroll
    for (int k = 0; k < 16; ++k) {
      int nl = ng*16 + k;
      float y = C.xs[0][nl]*w0 + C.xs[1][nl]*w1 + C.xs[2][nl]*w2;
      t1[((size_t)b*N_ + n0 + nl)*64 + o] = y;
      ls += y; lq += y*y;
    }
    C.redS[ng][o] = ls; C.redQ[ng][o] = lq;
    __syncthreads();
    if (t < 64) {
      float s = C.redS[0][t]+C.redS[1][t]+C.redS[2][t]+C.redS[3][t];
      float q = C.redQ[0][t]+C.redQ[1][t]+C.redQ[2][t]+C.redQ[3][t];
      atomicAdd(&stats[S_BN1 + t], s);
      atomicAdd(&stats[S_BN1 + 64 + t], q);
    }
    __syncthreads();
  }
  if (t == 0) {
    __threadfence();
    __hip_atomic_fetch_add(&cnt[0], 1, __ATOMIC_ACQ_REL, __HIP_MEMORY_SCOPE_AGENT);
    while (__hip_atomic_load(&cnt[0], __ATOMIC_ACQUIRE, __HIP_MEMORY_SCOPE_AGENT) < 256)
      __builtin_amdgcn_s_sleep(8);
    __threadfence();
  }
  __syncthreads();
  if (t < 64) {
    float m = stats[S_BN1 + t] * (1.f/32768.f);
    float v = stats[S_BN1 + 64 + t] * (1.f/32768.f) - m*m;
    float s = bn1g[t] * rsqrtf(v + EPS_);
    C.sc[t] = s; C.sh[t] = bn1b[t] - m*s;
  }
  __syncthreads();
  for (int tile = cb; tile < 512; tile += 256) {
    int b = tile >> 6, n0 = (tile & 63) << 6;
    constexpr int P = 68;
    for (int e = t; e < 4096; e += 256) {
      int nl = e >> 6, c = e & 63;
      float v = t1[((size_t)b*N_ + n0 + nl)*64 + c];
      C.at[c*P + nl] = fmaxf(v*C.sc[c] + C.sh[c], 0.f);
    }
    __syncthreads();
    int o = t & 63, ng = t >> 6;
    float acc[16];
#pragma unroll
    for (int k = 0; k < 16; ++k) acc[k] = 0.f;
    for (int i = 0; i < 64; ++i) {
      float wv = wt2c[i*64 + o];
      const float* ar = &C.at[i*P + ng*16];
#pragma unroll
      for (int k = 0; k < 16; k += 4) {
        float4 a4 = *(const float4*)(ar + k);
        acc[k+0] += a4.x*wv; acc[k+1] += a4.y*wv;
        acc[k+2] += a4.z*wv; acc[k+3] += a4.w*wv;
      }
    }
    float ls = 0.f, lq = 0.f;
#pragma unroll
    for (int k = 0; k < 16; ++k) {
      float y = acc[k];
      t2[((size_t)b*N_ + n0 + ng*16 + k)*64 + o] = y;
      ls += y; lq += y*y;
    }
    C.redS[ng][o] = ls; C.redQ[ng][o] = lq;
    __syncthreads();
    if (t < 64) {
      float s = C.redS[0][t]+C.redS[1][t]+C.redS[2][t]+C.redS[3][t];
      float q = C.redQ[0][t]+C.redQ[1][t]+C.redQ[2][t]+C.redQ[3][t];
      atomicAdd(&stats[S_BN2 + t], s);
      atomicAdd(&stats[S_BN2 + 64 + t], q);
    }
    __syncthreads();
  }
  if (t == 0) {
    __threadfence();
    __hip_atomic_fetch_add(&cnt[1], 1, __ATOMIC_ACQ_REL, __HIP_MEMORY_SCOPE_AGENT);
    while (__hip_atomic_load(&cnt[1], __ATOMIC_ACQUIRE, __HIP_MEMORY_SCOPE_AGENT) < 256)
      __builtin_amdgcn_s_sleep(8);
    __threadfence();
  }
  __syncthreads();
  {
    int o = t & 63;
    float m = stats[S_BN2 + o] * (1.f/32768.f);
    float v = stats[S_BN2 + 64 + o] * (1.f/32768.f) - m*m;
    float s = bn2g[o] * rsqrtf(v + EPS_);
    float sh = bn2b[o] - m*s;
    for (int tile = cb; tile < 512; tile += 256)
#pragma unroll
      for (int j = 0; j < 16; ++j) {
        size_t idx = (size_t)tile*4096 + j*256 + t;
        t1[idx] = fmaxf(t2[idx]*s + sh, 0.f);
      }
  }
}

// ---------------- kNN: wave-per-query, fully in-register, zero barriers/LDS (round-10 proven) ----------------
template<int NDST, bool XLAY>
__device__ inline void wave_knn(const float* __restrict__ db,
                                float qx, float qy, float qz,
                                int* __restrict__ out32) {
  constexpr int K = NDST / 64;
  int lane = threadIdx.x & 63;
  float q2 = (qx*qx + qy*qy) + qz*qz;
  float d2r[K];
#pragma unroll
  for (int k = 0; k < K; ++k) {
    int j = lane + k*64;
    float xx, yy, zz;
    if (XLAY) { xx = db[j]; yy = db[NDST + j]; zz = db[2*NDST + j]; }
    else      { xx = db[j*3]; yy = db[j*3+1]; zz = db[j*3+2]; }
    float dot = (qx*xx + qy*yy) + qz*zz;
    float p2  = (xx*xx + yy*yy) + zz*zz;
    d2r[k] = (q2 - 2.f*dot) + p2;     // same expansion as reference
  }
  int myout = 0;
  for (int r = 0; r < 32; ++r) {
    float bv = 3e38f; int bi = lane;
#pragma unroll
    for (int k = 0; k < K; ++k) {
      float v = d2r[k];
      if (v < bv) { bv = v; bi = lane + k*64; }   // k ascending => lowest index on tie
    }
    unsigned khi = ~ford(bv), klo = ~(unsigned)bi;
    dpp_amax<0xB1>(khi, klo);
    dpp_amax<0x4E>(khi, klo);
    dpp_amax<0x141>(khi, klo);
    dpp_amax<0x140>(khi, klo);
    swz16_amax(khi, klo);
    x32_amax(khi, klo);                 // wave-uniform winner
    int Bi = (int)~klo;
    if (lane == r) myout = Bi;
#pragma unroll
    for (int k = 0; k < K; ++k)         // compile-time index; no scratch (rule #20)
      if (lane + k*64 == Bi) d2r[k] = 3e38f;
  }
  if (lane < 32) out32[lane] = myout;
}

__global__ __launch_bounds__(256) void knn_fused_kernel(
    const float* __restrict__ x, const float* __restrict__ nxyz,
    const int* __restrict__ sel2, int* __restrict__ knn1, int* __restrict__ knn2) {
  int wid = threadIdx.x >> 6;
  int blk = blockIdx.x;
  if (blk < 1024) {
    int q = blk*4 + wid;          // 0..4095
    int b = q >> 9, qi = q & 511;
    const float* qp = nxyz + ((size_t)b*NP1 + qi)*3;
    wave_knn<4096, true>(x + (size_t)b*3*N_, qp[0], qp[1], qp[2], knn1 + (size_t)q*32);
  } else {
    int q = (blk - 1024)*4 + wid; // 0..2047
    int b = q >> 8, qi = q & 255;
    int qrow = b*NP1 + sel2[b*NP2 + qi];
    const float* qp = nxyz + (size_t)qrow*3;
    wave_knn<512, false>(nxyz + (size_t)b*NP1*3, qp[0], qp[1], qp[2], knn2 + (size_t)q*32);
  }
}

// ---------------- GEMM1: gather(+center-sub) -> bf16 MFMA -> y (bf16, coalesced) + stats ----------------
template<int D, int PW, int NP, int SRCN, int SOFF>
__global__ __launch_bounds__(256) void gemm1_kernel(
    const float* __restrict__ pts, const int* __restrict__ knn,
    const int* __restrict__ cent, const short* __restrict__ bw,
    short* __restrict__ ybuf, float* __restrict__ stats) {
  constexpr int KB = D/8;
  __shared__ __align__(16) short As[64*D];
  __shared__ float cen_s[2*PW];
  __shared__ int kid_s[64];
  __shared__ float sstat[2*D];
  int t = threadIdx.x, blk = blockIdx.x;
  int g0 = blk*2;
  if (t < 64) {
    int grp = t >> 5, s = t & 31;
    kid_s[t] = knn[((size_t)(g0+grp))*32 + s];
  }
  for (int i = t; i < 2*PW; i += 256) {
    int grp = i / PW, d = i % PW;
    int g = g0 + grp; int b = g / NP; int ci = cent[g];
    cen_s[i] = pts[((size_t)b*SRCN + ci)*PW + d];
  }
  for (int i = t; i < 2*D; i += 256) sstat[i] = 0.f;
  __syncthreads();
  for (int task = t; task < 64*KB; task += 256) {
    int row = task / KB, c = task % KB;
    int grp = row >> 5;
    int g = g0 + grp; int b = g / NP;
    int d = c*8;
    float v0,v1,v2,v3,v4,v5,v6,v7;
    if (d < PW) {
      const float* src = pts + ((size_t)b*SRCN + kid_s[row])*PW + d;
      float4 x0 = *(const float4*)src, x1 = *(const float4*)(src+4);
      const float* cc = &cen_s[grp*PW + d];
      v0=x0.x-cc[0]; v1=x0.y-cc[1]; v2=x0.z-cc[2]; v3=x0.w-cc[3];
      v4=x1.x-cc[4]; v5=x1.y-cc[5]; v6=x1.z-cc[6]; v7=x1.w-cc[7];
    } else {
      const float* cc = &cen_s[grp*PW + d - PW];
      v0=cc[0]; v1=cc[1]; v2=cc[2]; v3=cc[3]; v4=cc[4]; v5=cc[5]; v6=cc[6]; v7=cc[7];
    }
    bhalf8 pk;
    pk[0]=f2bf(v0); pk[1]=f2bf(v1); pk[2]=f2bf(v2); pk[3]=f2bf(v3);
    pk[4]=f2bf(v4); pk[5]=f2bf(v5); pk[6]=f2bf(v6); pk[7]=f2bf(v7);
    int a16 = row*KB + (c ^ (row & 7));
    *(bhalf8*)&As[a16*8] = pk;
  }
  __syncthreads();
  int w = t >> 6, l = t & 63, lr = l & 15, lg = l >> 4;
  f32x4 acc[D/16];
#pragma unroll
  for (int ct = 0; ct < D/16; ++ct) acc[ct] = (f32x4){0.f,0.f,0.f,0.f};
  int r = w*16 + lr;
#pragma unroll
  for (int kg = 0; kg < D/32; ++kg) {
    int c = (kg*4 + lg) ^ (r & 7);
    bhalf8 af = *(const bhalf8*)&As[(r*KB + c)*8];
#pragma unroll
    for (int ct = 0; ct < D/16; ++ct) {
      bhalf8 bf = *(const bhalf8*)&bw[((size_t)(kg*4 + lg)*D + ct*16 + lr)*8];
      acc[ct] = __builtin_amdgcn_mfma_f32_16x16x32_bf16(af, bf, acc[ct], 0, 0, 0);
    }
  }
  __syncthreads();   // all As reads complete; reuse As as bf16 C tile
  int lrow = w*16 + lg*4;
#pragma unroll
  for (int ct = 0; ct < D/16; ++ct) {
    int col = ct*16 + lr;
    f32x4 a = acc[ct];
    As[(lrow+0)*D + col] = f2bf(a[0]);
    As[(lrow+1)*D + col] = f2bf(a[1]);
    As[(lrow+2)*D + col] = f2bf(a[2]);
    As[(lrow+3)*D + col] = f2bf(a[3]);
    float s = a[0]+a[1]+a[2]+a[3];
    float q = a[0]*a[0]+a[1]*a[1]+a[2]*a[2]+a[3]*a[3];
    s += __shfl_xor(s, 16); q += __shfl_xor(q, 16);
    s += __shfl_xor(s, 32); q += __shfl_xor(q, 32);
    if (lg == 0) { atomicAdd(&sstat[col], s); atomicAdd(&sstat[D+col], q); }
  }
  __syncthreads();
  // coalesced bf16 C store
  {
    short* yp = ybuf + (size_t)blk*64*D;
    for (int i = t; i < 64*D/8; i += 256)
      *(bhalf8*)&yp[i*8] = *(const bhalf8*)&As[i*8];
  }
  for (int i = t; i < 2*D; i += 256) atomicAdd(&stats[SOFF+i], sstat[i]);
}

// ---------------- GEMM2: bf16 y-in, bn+relu on the fly -> bf16 MFMA -> per-group max/min + stats ----------------
template<int D, int SIN, int SOUT, int CNT>
__global__ __launch_bounds__(256) void gemm2_kernel(
    const float* __restrict__ g1, const float* __restrict__ b1,
    const short* __restrict__ bw, const short* __restrict__ ybuf,
    float* __restrict__ mm, float* __restrict__ stats) {
  __shared__ __align__(16) float scsh[2*D];
  __shared__ float sstat[2*D];
  __shared__ float wmax[4][D], wmin[4][D];
  int t = threadIdx.x, blk = blockIdx.x;
  for (int i = t; i < D; i += 256) {
    float m = stats[SIN + i] * (1.f/(float)CNT);
    float v = stats[SIN + D + i] * (1.f/(float)CNT) - m*m;
    float s = g1[i] * rsqrtf(v + EPS_);
    scsh[i] = s; scsh[D+i] = b1[i] - m*s;
  }
  for (int i = t; i < 2*D; i += 256) sstat[i] = 0.f;
  __syncthreads();
  int w = t >> 6, l = t & 63, lr = l & 15, lg = l >> 4;
  size_t row = (size_t)blk*64 + w*16 + lr;
  const short* yrow = ybuf + row*D;
  f32x4 acc[D/16];
#pragma unroll
  for (int ct = 0; ct < D/16; ++ct) acc[ct] = (f32x4){0.f,0.f,0.f,0.f};
#pragma unroll
  for (int kg = 0; kg < D/32; ++kg) {
    int k = kg*32 + lg*8;
    bhalf8 yv = *(const bhalf8*)(yrow + k);
    bhalf8 af;
#pragma unroll
    for (int j = 0; j < 8; ++j)
      af[j] = f2bf(fmaxf(bf2f(yv[j])*scsh[k+j] + scsh[D+k+j], 0.f));
#pragma unroll
    for (int ct = 0; ct < D/16; ++ct) {
      bhalf8 bf = *(const bhalf8*)&bw[((size_t)(kg*4 + lg)*D + ct*16 + lr)*8];
      acc[ct] = __builtin_amdgcn_mfma_f32_16x16x32_bf16(af, bf, acc[ct], 0, 0, 0);
    }
  }
#pragma unroll
  for (int ct = 0; ct < D/16; ++ct) {
    int col = ct*16 + lr;
    f32x4 a = acc[ct];
    float mx = fmaxf(fmaxf(a[0], a[1]), fmaxf(a[2], a[3]));
    float mn = fminf(fminf(a[0], a[1]), fminf(a[2], a[3]));
    mx = fmaxf(mx, __shfl_xor(mx, 16)); mn = fminf(mn, __shfl_xor(mn, 16));
    mx = fmaxf(mx, __shfl_xor(mx, 32)); mn = fminf(mn, __shfl_xor(mn, 32));
    if (lg == 0) { wmax[w][col] = mx; wmin[w][col] = mn; }
    float s = a[0]+a[1]+a[2]+a[3];
    float q = a[0]*a[0]+a[1]*a[1]+a[2]*a[2]+a[3]*a[3];
    s += __shfl_xor(s, 16); q += __shfl_xor(q, 16);
    s += __shfl_xor(s, 32); q += __shfl_xor(q, 32);
    if (lg == 0) { atomicAdd(&sstat[col], s); atomicAdd(&sstat[D+col], q); }
  }
  __syncthreads();
  for (int i = t; i < 2*D; i += 256) {
    int g = i / D, col = i - g*D;
    float mx = fmaxf(wmax[2*g][col], wmax[2*g+1][col]);
    float mn = fminf(wmin[2*g][col], wmin[2*g+1][col]);
    float* mp = mm + ((size_t)blk*2 + g)*2*D;
    mp[col] = mx; mp[D + col] = mn;
    atomicAdd(&stats[SOUT+i], sstat[i]);
  }
}

// ---------------- finish: bn2 + relu applied to per-group max/min (exact, elementwise) ----------------
template<int D, int NP, int SOFF, int CNT, bool TR>
__global__ __launch_bounds__(256) void le3_kernel(
    const float* __restrict__ g2, const float* __restrict__ b2,
    const float* __restrict__ mm, const float* __restrict__ stats,
    float* __restrict__ out) {
  int idx = blockIdx.x*256 + threadIdx.x;
  int g = idx / D, o = idx - g*D;
  float m = stats[SOFF + o] * (1.f/(float)CNT);
  float v = stats[SOFF + D + o] * (1.f/(float)CNT) - m*m;
  float s = g2[o] * rsqrtf(v + EPS_);
  float sh = b2[o] - m*s;
  const float* mp = mm + (size_t)g*2*D;
  float pick = (s >= 0.f) ? mp[o] : mp[D + o];
  float r = fmaxf(pick*s + sh, 0.f);
  if (TR) { int b = g / NP, n = g - b*NP; out[((size_t)b*D + o)*NP + n] = r; }
  else    out[(size_t)g*D + o] = r;
}

// ---------------- host ----------------
extern "C" void kernel_launch(void* const* d_in, const int* in_sizes, int n_in,
                              void* d_out, int out_size, void* d_ws, size_t ws_size,
                              hipStream_t stream) {
  (void)in_sizes; (void)n_in; (void)out_size; (void)ws_size;
  const float* x       = (const float*)d_in[0];
  const float* conv1_w = (const float*)d_in[1];
  const float* bn1_g   = (const float*)d_in[2];
  const float* bn1_b   = (const float*)d_in[3];
  const float* conv2_w = (const float*)d_in[4];
  const float* bn2_g   = (const float*)d_in[5];
  const float* bn2_b   = (const float*)d_in[6];
  const float* le0_w1  = (const float*)d_in[7];
  const float* le0_g1  = (const float*)d_in[8];
  const float* le0_b1  = (const float*)d_in[9];
  const float* le0_w2  = (const float*)d_in[10];
  const float* le0_g2  = (const float*)d_in[11];
  const float* le0_b2  = (const float*)d_in[12];
  const float* le1_w1  = (const float*)d_in[13];
  const float* le1_g1  = (const float*)d_in[14];
  const float* le1_b1  = (const float*)d_in[15];
  const float* le1_w2  = (const float*)d_in[16];
  const float* le1_g2  = (const float*)d_in[17];
  const float* le1_b2  = (const float*)d_in[18];

  float* ws   = (float*)d_ws;
  float* t1   = ws + OFF_T1;      // conv1 out; then 'pts'; later mm buffer
  float* t2   = ws + OFF_YBUF;    // conv2 f32 buffer (front phase)
  short* ybuf = (short*)(ws + OFF_YBUF);  // LE y1 buffer, bf16 (tail phase)
  float* mm   = t1;
  float* pts1 = ws + OFF_PTS1;
  float* nxyz = ws + OFF_NXYZ;
  float* wt2c = ws + OFF_WT2C;
  short* bw0a = (short*)(ws + OFF_BW0A);
  short* bw0b = (short*)(ws + OFF_BW0B);
  short* bw1a = (short*)(ws + OFF_BW1A);
  short* bw1b = (short*)(ws + OFF_BW1B);
  float* stats = ws + OFF_STAT;
  int*   cnt   = (int*)(ws + OFF_CNT);
  int* fps1 = (int*)(ws + OFF_INT);
  int* fps2 = fps1 + 4096;
  int* knn1 = fps2 + 2048;
  int* knn2 = knn1 + 131072;

  // zero stats + barrier counters (captured; re-zeroed on every replay)
  hipMemsetAsync(stats, 0, (S_TOTAL + 32)*sizeof(float), stream);
  front_kernel<<<264, 256, 0, stream>>>(x,
      conv1_w, bn1_g, bn1_b, conv2_w, bn2_g, bn2_b,
      le0_w1, le0_w2, le1_w1, le1_w2,
      wt2c, bw0a, bw0b, bw1a, bw1b,
      t1, t2, stats, cnt, fps1, nxyz, fps2);

  knn_fused_kernel<<<1536, 256, 0, stream>>>(x, nxyz, fps2, knn1, knn2);

  gemm1_kernel<128,  64, 512, 4096, S_L0A><<<2048, 256, 0, stream>>>(t1, knn1, fps1, bw0a, ybuf, stats);
  gemm2_kernel<128, S_L0A, S_L0B, 131072><<<2048, 256, 0, stream>>>(le0_g1, le0_b1, bw0b, ybuf, mm, stats);
  le3_kernel<128, 512, S_L0B, 131072, false><<<2048, 256, 0, stream>>>(le0_g2, le0_b2, mm, stats, pts1);

  gemm1_kernel<256, 128, 256,  512, S_L1A><<<1024, 256, 0, stream>>>(pts1, knn2, fps2, bw1a, ybuf, stats);
  gemm2_kernel<256, S_L1A, S_L1B, 65536><<<1024, 256, 0, stream>>>(le1_g1, le1_b1, bw1b, ybuf, mm, stats);
  le3_kernel<256, 256, S_L1B, 65536, true><<<2048, 256, 0, stream>>>(le1_g2, le1_b2, mm, stats, (float*)d_out);
}